// Round 1
// baseline (208.396 us; speedup 1.0000x reference)
//
#include <hip/hip_runtime.h>

// ---------------------------------------------------------------------------
// out[n] = x_n^T A x_n / (x_n^T x_n),  A = Re(U^H Z U), U = full circuit unitary
// Kernel 1: simulate circuit on 128 basis columns -> U (complex fp32) in ws
// Kernel 2: A_ij = sum_k z_k (Ur_ki Ur_kj + Ui_ki Ui_kj) -> bf16 A in ws
// Kernel 3: bf16 MFMA GEMM y = A x fused with dot/norm epilogue
//
// R6 -> R7: R6 measured 205 us vs a ~21 us HBM roofline (134 MB once) ->
// latency/serialization-bound, not BW-bound. R6 exposed a full HBM latency
// every iteration: vmcnt(0) + __syncthreads drained ALL outstanding DMA with
// prefetch distance 1. R7 restructures kernel 3 around T3/T4 (counted vmcnt,
// never 0 in the main loop):
//   - per-WAVE staging: wave w DMAs its own 16 rows -> no cross-wave LDS
//     dependency -> zero __syncthreads in the whole kernel.
//   - A-fragments are loop-invariant -> hoisted to 128 VGPRs, loaded once
//     directly from L2-resident Ab. Kills the 32KB As LDS, its fill+barrier,
//     and 32 LDS reads/iter. LDS still 64 KB (4 X buffers) -> 2 blocks/CU,
//     1 wave/SIMD -> VGPR budget 512, no spill at ~230.
//   - DEPTH=4 X pipeline: 3 tiles (24 KB/wave) in flight; s_waitcnt vmcnt(24)
//     steady state (8 DMA/tile/wave, in-order retirement => tile it complete),
//     tail 16/8/0. The in-loop predicated store only ADDS newer vmcnt ops =>
//     the counted wait stays conservative under any legal scheduling.
//   - buffer-reuse WAR is safe: stage(it+3) overwrites the buffer read at
//     it-1; the DMA LDS-write lands >=global-latency after an issue point
//     that is program-order after those ds_reads, and staging is wave-private.
// Predicted: vqa_main ~190 -> 30-60 us, hbm_gbps 0.7 -> >=2 TB/s.
// ---------------------------------------------------------------------------

#define N_QUBITS 7
#define DIM 128
#define N_LAYERS 4
#define BATCH 262144
#define GRID 512
#define ROWS 32                          // rows per X tile
#define ITERS (BATCH / (GRID * ROWS))    // 16
#define DEPTH 4                          // X tile buffers in LDS

typedef short short8 __attribute__((ext_vector_type(8)));
typedef float f32x4 __attribute__((ext_vector_type(4)));
typedef unsigned int u32;
typedef __attribute__((address_space(1))) const u32 g_u32;
typedef __attribute__((address_space(3))) u32 l_u32;

__device__ __forceinline__ unsigned short f2bf(float f) {
  unsigned u = __builtin_bit_cast(unsigned, f);
  u += 0x7fffu + ((u >> 16) & 1u);   // RNE
  return (unsigned short)(u >> 16);
}

// [bf16(x) | bf16(y)<<16]: round-half-up add + v_perm byte select
__device__ __forceinline__ unsigned pk2(float x, float y) {
  unsigned ux = __builtin_bit_cast(unsigned, x) + 0x8000u;
  unsigned uy = __builtin_bit_cast(unsigned, y) + 0x8000u;
  return __builtin_amdgcn_perm(uy, ux, 0x07060302u);
}

__device__ __forceinline__ short8 pack_bf16(float4 lo, float4 hi) {
  uint4 d;
  d.x = pk2(lo.x, lo.y);
  d.y = pk2(lo.z, lo.w);
  d.z = pk2(hi.x, hi.y);
  d.w = pk2(hi.z, hi.w);
  return __builtin_bit_cast(short8, d);
}

// ---------------------------------------------------------------------------
// Kernel 1: one block (64 threads) per column c. State (128 complex) in LDS.
// Qubit w <-> bit (6-w) of the flattened index.  (unchanged, verified)
// ---------------------------------------------------------------------------
__global__ void sim_columns(const float* __restrict__ W,
                            float* __restrict__ Ur, float* __restrict__ Ui) {
  __shared__ float sr[DIM], si[DIM];
  const int c = blockIdx.x;
  const int t = threadIdx.x;  // 0..63

  sr[t] = (t == c) ? 1.f : 0.f;        si[t] = 0.f;
  sr[t + 64] = (t + 64 == c) ? 1.f : 0.f;  si[t + 64] = 0.f;
  __syncthreads();

  for (int l = 0; l < N_LAYERS; ++l) {
    for (int w = 0; w < N_QUBITS; ++w) {
      const float phi = W[(l * 7 + w) * 3 + 0];
      const float th  = W[(l * 7 + w) * 3 + 1];
      const float om  = W[(l * 7 + w) * 3 + 2];
      const float ch = __cosf(0.5f * th), sh = __sinf(0.5f * th);
      const float ap = 0.5f * (phi + om), am = 0.5f * (phi - om);
      const float cap = __cosf(ap), sap = __sinf(ap);
      const float cam = __cosf(am), sam = __sinf(am);
      const float ar =  cap * ch, ai = -sap * ch;
      const float br = -cam * sh, bi = -sam * sh;
      const float cr =  cam * sh, ci = -sam * sh;
      const float dr =  cap * ch, di =  sap * ch;

      const int m = 1 << (6 - w);
      const int i0 = ((t & ~(m - 1)) << 1) | (t & (m - 1));
      const int i1 = i0 | m;
      const float x0r = sr[i0], x0i = si[i0];
      const float x1r = sr[i1], x1i = si[i1];
      __syncthreads();
      sr[i0] = ar * x0r - ai * x0i + br * x1r - bi * x1i;
      si[i0] = ar * x0i + ai * x0r + br * x1i + bi * x1r;
      sr[i1] = cr * x0r - ci * x0i + dr * x1r - di * x1i;
      si[i1] = cr * x0i + ci * x0r + dr * x1i + di * x1r;
      __syncthreads();
    }
    const int r = (l % (N_QUBITS - 1)) + 1;  // ranges [1,2,3,4]
    for (int w = 0; w < N_QUBITS; ++w) {
      const int ctrl = w, tgt = (w + r) % N_QUBITS;
      const int cmask = 1 << (6 - ctrl), tmask = 1 << (6 - tgt);
      const int i0 = ((t & ~(tmask - 1)) << 1) | (t & (tmask - 1));
      const int i1 = i0 | tmask;
      const float a0r = sr[i0], a0i = si[i0];
      const float a1r = sr[i1], a1i = si[i1];
      __syncthreads();
      if (i0 & cmask) {
        sr[i0] = a1r; si[i0] = a1i;
        sr[i1] = a0r; si[i1] = a0i;
      }
      __syncthreads();
    }
  }
  Ur[(size_t)t * DIM + c]        = sr[t];
  Ui[(size_t)t * DIM + c]        = si[t];
  Ur[(size_t)(t + 64) * DIM + c] = sr[t + 64];
  Ui[(size_t)(t + 64) * DIM + c] = si[t + 64];
}

// ---------------------------------------------------------------------------
// Kernel 2: A_ij, identity k-layout. 128 blocks (row i) x 128 threads (j).
// Ur[k][i] broadcasts; Ur[k][j] coalesces; all L2-hot.  (unchanged, verified)
// ---------------------------------------------------------------------------
__global__ void build_A(const float* __restrict__ Ur, const float* __restrict__ Ui,
                        unsigned short* __restrict__ Ab) {
  const int i = blockIdx.x;
  const int j = threadIdx.x;
  float s = 0.f;
#pragma unroll 8
  for (int k = 0; k < DIM; ++k) {
    const float zk = (((k >> 6) ^ k) & 1) ? -1.f : 1.f;
    s += zk * (Ur[k * DIM + i] * Ur[k * DIM + j] + Ui[k * DIM + i] * Ui[k * DIM + j]);
  }
  Ab[i * DIM + j] = f2bf(s);
}

// ---------------------------------------------------------------------------
// Per-WAVE stage of one tile's half (the wave's own 16 rows = 8 KB = 8 DMAs).
// LDS slot s (16B units, s in [512w, 512w+512)) holds global chunk
// (row = s>>5, c = (s&31) ^ (row&7)) -- source-side swizzle because the DMA's
// LDS dest is wave-uniform base + lane*16 (m104) and can't scatter. Per DMA
// the 64 lane dests are contiguous 16B slots in lane order, as HW requires.
// ---------------------------------------------------------------------------
__device__ __forceinline__ void stage_half(const float* __restrict__ X, float* XsBuf,
                                           int tile, int wave, int lane) {
#pragma unroll
  for (int j = 0; j < 8; ++j) {
    const int s = 512 * wave + 64 * j + lane;   // slot id within this buffer
    const int row = s >> 5;
    const int c = (s & 31) ^ (row & 7);         // swizzled source chunk
    const float* gp = X + (size_t)tile * (ROWS * DIM) + row * DIM + c * 4;
    __builtin_amdgcn_global_load_lds((g_u32*)gp, (l_u32*)(XsBuf + s * 4), 16, 0, 0);
  }
}

// ---------------------------------------------------------------------------
// Kernel 3. Block = 2 waves; wave w owns tile rows 16w..16w+15. No barriers.
//   A-frag: a_frag[kt][t] = Ab[16t + n16][32kt + 8g .. +8], held in 128 VGPRs
//           (loaded once, directly from global; Ab is 32 KB, L2-resident)
//   B-frag: row R = 16w + n16, chunks (8kt+2g)^rx, (8kt+2g+1)^rx (2x b128)
//   C/D:    acc[t][r] = y[16t + 4g + r][n16]; epilogue xe chunk (4t+g)^rx.
// Quarter-wave read phases (fixed g, R over 16 rows): (c0 ^ (R&7)) covers
// every 4-bank group exactly twice = 2-way = free (m136).
// DEPTH=4 rotating buffers; counted s_waitcnt vmcnt(24/16/8/0) per wave.
// ---------------------------------------------------------------------------
__global__ __launch_bounds__(128, 1) void vqa_main(const float* __restrict__ X,
                                                   const unsigned short* __restrict__ Ab,
                                                   float* __restrict__ out) {
  __shared__ float Xs[DEPTH * ROWS * DIM];   // 4 x 16 KB = 64 KB

  const int tid = threadIdx.x;   // 0..127
  const int lane = tid & 63;
  const int wave = tid >> 6;     // 0..1
  const int n16 = lane & 15;
  const int g = lane >> 4;
  const int R = 16 * wave + n16; // this lane's row within the tile (0..31)
  const int rx = R & 7;          // row swizzle key

  // loop-invariant A fragments -> registers (32 x 16 B = 128 VGPRs)
  short8 a_frag[4][8];
#pragma unroll
  for (int kt = 0; kt < 4; ++kt)
#pragma unroll
    for (int t = 0; t < 8; ++t)
      a_frag[kt][t] = *reinterpret_cast<const short8*>(
          Ab + (16 * t + n16) * DIM + 32 * kt + 8 * g);

  // prologue: stage tiles 0..DEPTH-2 of this wave's half rows
#pragma unroll
  for (int p = 0; p < DEPTH - 1; ++p)
    stage_half(X, Xs + p * (ROWS * DIM), blockIdx.x + p * GRID, wave, lane);

#pragma unroll 1
  for (int it = 0; it < ITERS; ++it) {
    const int cur = it & (DEPTH - 1);

    // issue tile it+3's DMA into the rotating buffer (wave-private rows)
    if (it + DEPTH - 1 < ITERS)
      stage_half(X, Xs + ((it + DEPTH - 1) & (DEPTH - 1)) * (ROWS * DIM),
                 blockIdx.x + (it + DEPTH - 1) * GRID, wave, lane);

    // counted wait: 8 DMAs/tile/wave, in-order retirement => tile it landed.
    // In-loop stores only ADD newer vmcnt ops => thresholds stay conservative.
    const int rem = ITERS - 1 - it;
    if (rem >= DEPTH - 1)  asm volatile("s_waitcnt vmcnt(24)" ::: "memory");
    else if (rem == 2)     asm volatile("s_waitcnt vmcnt(16)" ::: "memory");
    else if (rem == 1)     asm volatile("s_waitcnt vmcnt(8)"  ::: "memory");
    else                   asm volatile("s_waitcnt vmcnt(0)"  ::: "memory");

    const int rb = cur * (ROWS * 32) + R * 32;   // row's first slot in cur buf

    // B-fragments from LDS
    short8 bfrag[4];
#pragma unroll
    for (int kt = 0; kt < 4; ++kt) {
      const int c0 = 8 * kt + 2 * g;
      const float4 lo = *reinterpret_cast<const float4*>(Xs + (rb + (c0 ^ rx)) * 4);
      const float4 hi = *reinterpret_cast<const float4*>(Xs + (rb + ((c0 + 1) ^ rx)) * 4);
      bfrag[kt] = pack_bf16(lo, hi);
    }

    f32x4 acc[8];
#pragma unroll
    for (int t = 0; t < 8; ++t) acc[t] = (f32x4){0.f, 0.f, 0.f, 0.f};
#pragma unroll
    for (int kt = 0; kt < 4; ++kt) {
#pragma unroll
      for (int t = 0; t < 8; ++t)
        acc[t] = __builtin_amdgcn_mfma_f32_16x16x32_bf16(a_frag[kt][t], bfrag[kt],
                                                         acc[t], 0, 0, 0);
    }

    // epilogue: x re-read from cur buffer (not overwritten until it+1's stage)
    float dot = 0.f, nrm = 0.f;
#pragma unroll
    for (int t = 0; t < 8; ++t) {
      const float4 xe = *reinterpret_cast<const float4*>(Xs + (rb + ((4 * t + g) ^ rx)) * 4);
      dot += xe.x * acc[t][0] + xe.y * acc[t][1] + xe.z * acc[t][2] + xe.w * acc[t][3];
      nrm += xe.x * xe.x + xe.y * xe.y + xe.z * xe.z + xe.w * xe.w;
    }
    dot += __shfl_xor(dot, 16, 64);
    dot += __shfl_xor(dot, 32, 64);
    nrm += __shfl_xor(nrm, 16, 64);
    nrm += __shfl_xor(nrm, 32, 64);
    if (g == 0) out[(blockIdx.x + it * GRID) * ROWS + R] = dot / nrm;
  }
}

// ---------------------------------------------------------------------------
extern "C" void kernel_launch(void* const* d_in, const int* in_sizes, int n_in,
                              void* d_out, int out_size, void* d_ws, size_t ws_size,
                              hipStream_t stream) {
  const float* X = (const float*)d_in[0];   // (262144, 128) fp32
  const float* W = (const float*)d_in[1];   // (4, 7, 3) fp32
  float* out = (float*)d_out;               // (262144,) fp32

  float* Ur = (float*)d_ws;
  float* Ui = Ur + DIM * DIM;
  unsigned short* Ab = (unsigned short*)(Ui + DIM * DIM);

  sim_columns<<<DIM, 64, 0, stream>>>(W, Ur, Ui);
  build_A<<<DIM, DIM, 0, stream>>>(Ur, Ui, Ab);
  vqa_main<<<GRID, 128, 0, stream>>>(X, Ab, out);
}